// Round 2
// baseline (511.827 us; speedup 1.0000x reference)
//
#include <hip/hip_runtime.h>
#include <cstdint>
#include <cstddef>

// Problem constants (fixed by the reference)
#define N_NODES 10000
#define F_IN    512
#define NHID    32
#define LATENT  16

// ---------------------------------------------------------------------------
// GEMM1: h0 = x @ W1   [10000,512] x [512,32] -> [10000,32]
// block = 256 threads = 8 rows x 32 cols; x rows staged in LDS.
// ---------------------------------------------------------------------------
__global__ __launch_bounds__(256) void gemm1_kernel(const float* __restrict__ x,
                                                    const float* __restrict__ W1,
                                                    float* __restrict__ h0) {
    __shared__ float xs[8][F_IN];  // 16 KB
    const int row0 = blockIdx.x * 8;
    // cooperative coalesced load of 8 rows x 512 floats
    for (int t = threadIdx.x; t < 8 * F_IN; t += 256) {
        const int r = t >> 9;          // /512
        const int c = t & (F_IN - 1);  // %512
        if (row0 + r < N_NODES)
            xs[r][c] = x[(size_t)(row0 + r) * F_IN + c];
    }
    __syncthreads();

    const int col = threadIdx.x & 31;
    const int r   = threadIdx.x >> 5;
    if (row0 + r < N_NODES) {
        float acc = 0.f;
#pragma unroll 8
        for (int k = 0; k < F_IN; ++k) {
            acc += xs[r][k] * W1[k * NHID + col];
        }
        h0[(size_t)(row0 + r) * NHID + col] = acc;
    }
}

// ---------------------------------------------------------------------------
// SpMM (scatter form): hout[dst[e]][d] += w[e] * hin[src[e]][d]
// one thread per (edge, feature). D is a power of two (32 or 16).
// ---------------------------------------------------------------------------
template <int D>
__global__ __launch_bounds__(256) void spmm_kernel(const int* __restrict__ src,
                                                   const int* __restrict__ dst,
                                                   const float* __restrict__ w,
                                                   const float* __restrict__ hin,
                                                   float* __restrict__ hout,
                                                   int E) {
    const int idx = blockIdx.x * 256 + threadIdx.x;
    const int e = idx / D;   // D is constexpr pow2 -> shift
    const int d = idx & (D - 1);
    if (e < E) {
        const int s = src[e];
        const int t = dst[e];
        const float val = w[e] * hin[(size_t)s * D + d];
        atomicAdd(&hout[(size_t)t * D + d], val);
    }
}

// ---------------------------------------------------------------------------
// GEMM2: z0 = h @ W2   [10000,32] x [32,16] -> [10000,16]
// one thread per output element; W2 (512 floats) staged in LDS.
// ---------------------------------------------------------------------------
__global__ __launch_bounds__(256) void gemm2_kernel(const float* __restrict__ h,
                                                    const float* __restrict__ W2,
                                                    float* __restrict__ z0) {
    __shared__ float w2s[NHID * LATENT];
    for (int t = threadIdx.x; t < NHID * LATENT; t += 256) w2s[t] = W2[t];
    __syncthreads();

    const int idx = blockIdx.x * 256 + threadIdx.x;
    if (idx < N_NODES * LATENT) {
        const int row = idx >> 4;            // / LATENT
        const int col = idx & (LATENT - 1);  // % LATENT
        const float* __restrict__ hr = h + (size_t)row * NHID;
        float acc = 0.f;
#pragma unroll
        for (int k = 0; k < NHID; ++k) acc += hr[k] * w2s[k * LATENT + col];
        z0[idx] = acc;
    }
}

// ---------------------------------------------------------------------------
// Decoder: out[i][j] = sigmoid(dot(z[i], z[j])), N x N output.
// block = 256 threads, each owning one column j (z[j] in 16 VGPRs).
// Each block covers TI=32 rows i; z[i] loads are wave-uniform -> the
// compiler scalarizes them to s_load_dwordx4 (SGPR operands for the FMAs),
// so the VALU only pays 16 FMA + sigmoid + 1 store per output.
// Write-BW bound: 400 MB of stores (~63 us floor at 6.3 TB/s).
// ---------------------------------------------------------------------------
#define TI 32

__device__ __forceinline__ float sigmoid_fast(float x) {
    // 1/(1+exp(-x)); v_exp_f32 + v_rcp_f32.  Saturates correctly at +-inf.
    return __builtin_amdgcn_rcpf(1.0f + __expf(-x));
}

__global__ __launch_bounds__(256) void decoder_kernel(const float* __restrict__ z,
                                                      float* __restrict__ out) {
    const int j  = blockIdx.x * 256 + threadIdx.x;
    const int i0 = blockIdx.y * TI;

    float4 zj0, zj1, zj2, zj3;
    if (j < N_NODES) {
        const float4* __restrict__ zp = (const float4*)(z + (size_t)j * LATENT);
        zj0 = zp[0]; zj1 = zp[1]; zj2 = zp[2]; zj3 = zp[3];
    } else {
        zj0 = zj1 = zj2 = zj3 = make_float4(0.f, 0.f, 0.f, 0.f);
    }

    const int imax = min(TI, N_NODES - i0);
    if (imax == TI) {
#pragma unroll 4
        for (int ii = 0; ii < TI; ++ii) {
            const float4* __restrict__ zi = (const float4*)(z + (size_t)(i0 + ii) * LATENT);
            const float4 a0 = zi[0], a1 = zi[1], a2 = zi[2], a3 = zi[3];
            float acc = a0.x * zj0.x + a0.y * zj0.y + a0.z * zj0.z + a0.w * zj0.w
                      + a1.x * zj1.x + a1.y * zj1.y + a1.z * zj1.z + a1.w * zj1.w
                      + a2.x * zj2.x + a2.y * zj2.y + a2.z * zj2.z + a2.w * zj2.w
                      + a3.x * zj3.x + a3.y * zj3.y + a3.z * zj3.z + a3.w * zj3.w;
            if (j < N_NODES) {
                __builtin_nontemporal_store(sigmoid_fast(acc),
                                            &out[(size_t)(i0 + ii) * N_NODES + j]);
            }
        }
    } else {
        for (int ii = 0; ii < imax; ++ii) {
            const float4* __restrict__ zi = (const float4*)(z + (size_t)(i0 + ii) * LATENT);
            const float4 a0 = zi[0], a1 = zi[1], a2 = zi[2], a3 = zi[3];
            float acc = a0.x * zj0.x + a0.y * zj0.y + a0.z * zj0.z + a0.w * zj0.w
                      + a1.x * zj1.x + a1.y * zj1.y + a1.z * zj1.z + a1.w * zj1.w
                      + a2.x * zj2.x + a2.y * zj2.y + a2.z * zj2.z + a2.w * zj2.w
                      + a3.x * zj3.x + a3.y * zj3.y + a3.z * zj3.z + a3.w * zj3.w;
            if (j < N_NODES) {
                __builtin_nontemporal_store(sigmoid_fast(acc),
                                            &out[(size_t)(i0 + ii) * N_NODES + j]);
            }
        }
    }
}

// ---------------------------------------------------------------------------
// Launch: scratch (h0, h, z0) lives inside the adj-recon region of d_out,
// which the decoder fully overwrites last -> no dependence on ws_size.
// z accumulates directly into its final spot (tail of d_out).
// ---------------------------------------------------------------------------
extern "C" void kernel_launch(void* const* d_in, const int* in_sizes, int n_in,
                              void* d_out, int out_size, void* d_ws, size_t ws_size,
                              hipStream_t stream) {
    const float* x  = (const float*)d_in[0];   // [N, 512]
    const float* W1 = (const float*)d_in[1];   // [512, 32]
    const float* W2 = (const float*)d_in[2];   // [32, 16]
    const int*   ei = (const int*)d_in[3];     // [2, E]
    const float* ew = (const float*)d_in[4];   // [E]
    const int E = in_sizes[3] / 2;
    const int* src = ei;
    const int* dst = ei + E;

    float* out = (float*)d_out;                              // [N, N]
    float* z   = out + (size_t)N_NODES * N_NODES;            // [N, 16] (final tail)

    // scratch inside the adj region (overwritten by decoder at the end)
    float* h0 = out;                      // N*32 floats
    float* h  = h0 + N_NODES * NHID;      // N*32 floats
    float* z0 = h  + N_NODES * NHID;      // N*16 floats   (total 800k floats << N*N)

    // zero the atomic accumulators (d_out is poisoned before every launch)
    hipMemsetAsync(h, 0, (size_t)N_NODES * NHID * sizeof(float), stream);
    hipMemsetAsync(z, 0, (size_t)N_NODES * LATENT * sizeof(float), stream);

    // layer 1
    gemm1_kernel<<<(N_NODES + 7) / 8, 256, 0, stream>>>(x, W1, h0);
    spmm_kernel<NHID><<<(E * NHID + 255) / 256, 256, 0, stream>>>(src, dst, ew, h0, h, E);

    // layer 2
    gemm2_kernel<<<(N_NODES * LATENT + 255) / 256, 256, 0, stream>>>(h, W2, z0);
    spmm_kernel<LATENT><<<(E * LATENT + 255) / 256, 256, 0, stream>>>(src, dst, ew, z0, z, E);

    // decoder: adj_recon = sigmoid(z @ z^T)
    dim3 dgrid((N_NODES + 255) / 256, (N_NODES + TI - 1) / TI);
    decoder_kernel<<<dgrid, 256, 0, stream>>>(z, out);
}